// Round 3
// baseline (1033.298 us; speedup 1.0000x reference)
//
#include <hip/hip_runtime.h>

#define N_NODES 30000
#define N_EDGES 240000
#define NF 32
#define EF 16
#define HF 64
#define NC 8

#define EB_GRID  938   // (N_EDGES + 255) / 256
#define NB2_GRID 235   // (2*N_NODES + 255) / 256
#define NBLK     938   // main-loop blocks (~256 edges each, node-aligned)
#define ELDS_ROWS 384  // >= 256 + max_degree (max deg ~30 for Poisson(8))

// wbuf layout (float offsets)
#define W_COMB 0      // [16][16] We @ Wem[64:128)
#define B_COMB 256    // [16]     bem + be@Wem[64:128)
#define W_NC   272    // [16][32] We @ Wnm[0:64)
#define B_VEC  784    // [32]     be @ Wnm[0:64)
#define W_SD   816    // [32][32] cols 0-15: Wn@Wem[0:64) ; cols 16-31: Wn@Wem[128:192)
#define W_NB   1840   // [32][32] Wn @ Wnm[64:128)   (contiguous after W_SD)
#define B_SD   2864   // [32]     [bn@WemS | bn@WemD]
#define B_NB   2896   // [32]     bnm + bn@Wnm[64:128)
#define W_NF   2928   // [32][8]  Wn @ Wfc
#define B_NF   3184   // [8]      bfc + bn@Wfc

// precompute LDS staging layout (float offsets)
#define LWn   0       // 2048
#define LWe   2048    // 1024
#define LWem  3072    // 3072
#define LWnm  6144    // 4096
#define LWfc  10240   // 512
#define Lbn   10752   // 64
#define Lbe   10816   // 64
#define Lbem  10880   // 16
#define Lbnm  10896   // 32
#define Lbfc  10928   // 8
#define LTOT  10936

__device__ __forceinline__ float sigmoidf_(float x) {
  return 1.0f / (1.0f + __expf(-x));
}

// ---------------------------------------------------------------------------
// hist (blocks 0..EB-1) + precompute (block EB).
// Precompute now LDS-stages all weights with coalesced loads first (one
// latency round-trip) instead of ~700 scattered scalar cold loads.
// ---------------------------------------------------------------------------
__global__ void __launch_bounds__(256) hist_pre_kernel(
    const int* __restrict__ dst, int* __restrict__ cnt,
    const float* __restrict__ Wn, const float* __restrict__ bn,
    const float* __restrict__ We, const float* __restrict__ be,
    const float* __restrict__ Wem, const float* __restrict__ bem,
    const float* __restrict__ Wnm, const float* __restrict__ bnm,
    const float* __restrict__ Wfc, const float* __restrict__ bfc,
    float* __restrict__ wbuf) {
  __shared__ float sW[LTOT];
  if (blockIdx.x < EB_GRID) {
    int e = blockIdx.x * 256 + threadIdx.x;
    if (e < N_EDGES) atomicAdd(&cnt[dst[e]], 1);
    return;
  }
  int tid = threadIdx.x;
  for (int i = tid; i < 2048; i += 256) sW[LWn + i] = Wn[i];
  for (int i = tid; i < 1024; i += 256) sW[LWe + i] = We[i];
  for (int i = tid; i < 3072; i += 256) sW[LWem + i] = Wem[i];
  for (int i = tid; i < 4096; i += 256) sW[LWnm + i] = Wnm[i];
  for (int i = tid; i < 512; i += 256) sW[LWfc + i] = Wfc[i];
  if (tid < 64) sW[Lbn + tid] = bn[tid];
  if (tid < 64) sW[Lbe + tid] = be[tid];
  if (tid < 16) sW[Lbem + tid] = bem[tid];
  if (tid < 32) sW[Lbnm + tid] = bnm[tid];
  if (tid < 8)  sW[Lbfc + tid] = bfc[tid];
  __syncthreads();
  {  // Wcomb
    int r = tid >> 4, c = tid & 15;
    float acc = 0.f;
    for (int j = 0; j < HF; ++j)
      acc = fmaf(sW[LWe + r * HF + j], sW[LWem + (HF + j) * EF + c], acc);
    wbuf[W_COMB + tid] = acc;
  }
  for (int idx = tid; idx < EF * NF; idx += 256) {  // Wnc
    int r = idx >> 5, c = idx & 31;
    float acc = 0.f;
    for (int j = 0; j < HF; ++j)
      acc = fmaf(sW[LWe + r * HF + j], sW[LWnm + j * NF + c], acc);
    wbuf[W_NC + idx] = acc;
  }
  for (int idx = tid; idx < NF * NF; idx += 256) {  // WSD
    int r = idx >> 5, c = idx & 31;
    float acc = 0.f;
    if (c < EF) {
      for (int j = 0; j < HF; ++j)
        acc = fmaf(sW[LWn + r * HF + j], sW[LWem + j * EF + c], acc);
    } else {
      int cc = c - EF;
      for (int j = 0; j < HF; ++j)
        acc = fmaf(sW[LWn + r * HF + j], sW[LWem + (2 * HF + j) * EF + cc], acc);
    }
    wbuf[W_SD + idx] = acc;
  }
  for (int idx = tid; idx < NF * NF; idx += 256) {  // WnB
    int r = idx >> 5, c = idx & 31;
    float acc = 0.f;
    for (int j = 0; j < HF; ++j)
      acc = fmaf(sW[LWn + r * HF + j], sW[LWnm + (HF + j) * NF + c], acc);
    wbuf[W_NB + idx] = acc;
  }
  if (tid < NF * NC) {  // Wnf
    int r = tid >> 3, c = tid & 7;
    float acc = 0.f;
    for (int j = 0; j < HF; ++j)
      acc = fmaf(sW[LWn + r * HF + j], sW[LWfc + j * NC + c], acc);
    wbuf[W_NF + tid] = acc;
  }
  if (tid < EF) {  // bcomb
    float acc = sW[Lbem + tid];
    for (int j = 0; j < HF; ++j)
      acc = fmaf(sW[Lbe + j], sW[LWem + (HF + j) * EF + tid], acc);
    wbuf[B_COMB + tid] = acc;
  }
  if (tid < NF) {  // bvec
    float acc = 0.f;
    for (int j = 0; j < HF; ++j)
      acc = fmaf(sW[Lbe + j], sW[LWnm + j * NF + tid], acc);
    wbuf[B_VEC + tid] = acc;
  }
  if (tid < NF) {  // bSD
    float acc = 0.f;
    if (tid < EF) {
      for (int j = 0; j < HF; ++j)
        acc = fmaf(sW[Lbn + j], sW[LWem + j * EF + tid], acc);
    } else {
      int cc = tid - EF;
      for (int j = 0; j < HF; ++j)
        acc = fmaf(sW[Lbn + j], sW[LWem + (2 * HF + j) * EF + cc], acc);
    }
    wbuf[B_SD + tid] = acc;
  }
  if (tid < NF) {  // bNB
    float acc = sW[Lbnm + tid];
    for (int j = 0; j < HF; ++j)
      acc = fmaf(sW[Lbn + j], sW[LWnm + (HF + j) * NF + tid], acc);
    wbuf[B_NB + tid] = acc;
  }
  if (tid < NC) {  // bnf
    float acc = sW[Lbfc + tid];
    for (int j = 0; j < HF; ++j)
      acc = fmaf(sW[Lbn + j], sW[LWfc + j * NC + tid], acc);
    wbuf[B_NF + tid] = acc;
  }
}

// exclusive scan of cnt[30000] -> off[30001], cursor = copy of off
__global__ void __launch_bounds__(1024) scan_kernel(
    const int* __restrict__ cnt, int* __restrict__ off, int* __restrict__ cursor) {
  __shared__ int part[1024];
  int t = threadIdx.x;
  const int CH = (N_NODES + 1023) / 1024;   // 30
  int base = t * CH;
  int lc[CH];
  int sum = 0;
  for (int i = 0; i < CH; ++i) {
    int idx = base + i;
    lc[i] = (idx < N_NODES) ? cnt[idx] : 0;
    sum += lc[i];
  }
  part[t] = sum;
  __syncthreads();
  for (int ofs = 1; ofs < 1024; ofs <<= 1) {
    int v = (t >= ofs) ? part[t - ofs] : 0;
    __syncthreads();
    part[t] += v;
    __syncthreads();
  }
  int run = (t == 0) ? 0 : part[t - 1];
  for (int i = 0; i < CH; ++i) {
    int idx = base + i;
    if (idx < N_NODES) {
      off[idx] = run;
      cursor[idx] = run;
      run += lc[i];
    }
  }
  if (t == 1023) off[N_NODES] = part[1023];
}

// ---------------------------------------------------------------------------
// scatter (blocks 0..EB-1) + init_proj (blocks EB..EB+NB2-1) + nstart
// (block EB+NB2): nstart[b] = lower_bound(off, b*256) — node-aligned chunk
// boundaries for the block-centric main loop.
// ---------------------------------------------------------------------------
__global__ void __launch_bounds__(256) scatter_init_kernel(
    const float* __restrict__ edge_feat, const int* __restrict__ src,
    const int* __restrict__ dst, int* __restrict__ cursor,
    unsigned short* __restrict__ src_s, unsigned short* __restrict__ dst_s,
    float* __restrict__ e_buf,
    const float* __restrict__ node_feat, const float* __restrict__ wbuf,
    float* __restrict__ Ps, float* __restrict__ Pd, float* __restrict__ hpart,
    const int* __restrict__ off, int* __restrict__ nstart) {
  if (blockIdx.x < EB_GRID) {
    int e = blockIdx.x * 256 + threadIdx.x;
    if (e >= N_EDGES) return;
    int d = dst[e];
    int pos = atomicAdd(&cursor[d], 1);
    src_s[pos] = (unsigned short)src[e];
    dst_s[pos] = (unsigned short)d;
    const float4* ep = (const float4*)(edge_feat + (size_t)e * EF);
    float4* op = (float4*)(e_buf + (size_t)pos * EF);
    op[0] = ep[0]; op[1] = ep[1]; op[2] = ep[2]; op[3] = ep[3];
    return;
  }
  if (blockIdx.x == EB_GRID + NB2_GRID) {
    // nstart[b] for b in [0, NBLK]: smallest n with off[n] >= b*256 (clamped)
    for (int b = threadIdx.x; b <= NBLK; b += 256) {
      int v = b * 256;
      int lo = 0, hi = N_NODES;
      while (lo < hi) {
        int mid = (lo + hi) >> 1;
        if (off[mid] < v) lo = mid + 1; else hi = mid;
      }
      nstart[b] = lo;
    }
    return;
  }
  __shared__ float sPRJ[2048];
  __shared__ float sPB[64];
  for (int i = threadIdx.x; i < 2048; i += 256) sPRJ[i] = wbuf[W_SD + i];
  if (threadIdx.x < 64) sPB[threadIdx.x] = wbuf[B_SD + threadIdx.x];
  __syncthreads();
  int gid = (blockIdx.x - EB_GRID) * 256 + threadIdx.x;
  int n = gid >> 1, p = gid & 1;
  if (n >= N_NODES) return;
  float x[NF];
  const float4* xp = (const float4*)(node_feat + (size_t)n * NF);
#pragma unroll
  for (int k4 = 0; k4 < 8; ++k4) {
    float4 v = xp[k4];
    x[4 * k4] = v.x; x[4 * k4 + 1] = v.y; x[4 * k4 + 2] = v.z; x[4 * k4 + 3] = v.w;
  }
  float pr[NF];
  const float* pb = sPB + p * 32;
#pragma unroll
  for (int j = 0; j < NF; ++j) pr[j] = pb[j];
  const float* wbase = sPRJ + p * 1024;
  for (int k = 0; k < NF; ++k) {
    float v = x[k];
    const float4* wr = (const float4*)(wbase + k * NF);
#pragma unroll
    for (int j4 = 0; j4 < 8; ++j4) {
      float4 w = wr[j4];
      pr[4 * j4 + 0] = fmaf(v, w.x, pr[4 * j4 + 0]);
      pr[4 * j4 + 1] = fmaf(v, w.y, pr[4 * j4 + 1]);
      pr[4 * j4 + 2] = fmaf(v, w.z, pr[4 * j4 + 2]);
      pr[4 * j4 + 3] = fmaf(v, w.w, pr[4 * j4 + 3]);
    }
  }
  if (p == 0) {
    float4* a = (float4*)(Ps + (size_t)n * EF);
    a[0] = make_float4(pr[0], pr[1], pr[2], pr[3]);
    a[1] = make_float4(pr[4], pr[5], pr[6], pr[7]);
    a[2] = make_float4(pr[8], pr[9], pr[10], pr[11]);
    a[3] = make_float4(pr[12], pr[13], pr[14], pr[15]);
    float4* b = (float4*)(Pd + (size_t)n * EF);
    b[0] = make_float4(pr[16], pr[17], pr[18], pr[19]);
    b[1] = make_float4(pr[20], pr[21], pr[22], pr[23]);
    b[2] = make_float4(pr[24], pr[25], pr[26], pr[27]);
    b[3] = make_float4(pr[28], pr[29], pr[30], pr[31]);
  } else {
    float4* h = (float4*)(hpart + (size_t)n * NF);
#pragma unroll
    for (int j4 = 0; j4 < 8; ++j4)
      h[j4] = make_float4(pr[4 * j4], pr[4 * j4 + 1], pr[4 * j4 + 2], pr[4 * j4 + 3]);
  }
}

// ---------------------------------------------------------------------------
// Block-centric fused pass i: block b owns nodes [nstart[b], nstart[b+1])
// and their contiguous (dst-sorted) edges [off[ns0], off[ns1]) (<=383 rows).
// 1) stage e rows -> LDS (coalesced, read ONCE per pass)
// 2) node phase: segsum from LDS (no global gather), z/sigmoid/projections
// 3) edge phase: e' = sigmoid(bcomb + e@Wcomb + Ps[src] + Pd[dst]) -> e_dst
// Dependencies identical to previous fused kernel (e double-buffer, P
// ping-pong); hpart read(p0)-before-write(p1) preserved in wave order.
// ---------------------------------------------------------------------------
__global__ void __launch_bounds__(256) fused2_kernel(
    const float* __restrict__ e_src, float* __restrict__ e_dst,
    const unsigned short* __restrict__ src_s, const unsigned short* __restrict__ dst_s,
    const float* __restrict__ Ps_cur, const float* __restrict__ Pd_cur,
    float* __restrict__ hpart, const int* __restrict__ off,
    const int* __restrict__ nstart, const float* __restrict__ wbuf,
    float* __restrict__ Ps_next, float* __restrict__ Pd_next) {
  __shared__ __align__(16) float eL[ELDS_ROWS * EF];   // 24 KB
  __shared__ float sPRJ[2048];
  __shared__ float sWnc[EF * NF];
  __shared__ float sWC[EF * EF];
  __shared__ float sPB[64];
  __shared__ float sbvec[NF];
  __shared__ float sBC[EF];
  int t = threadIdx.x;
  for (int i = t; i < 2048; i += 256) sPRJ[i] = wbuf[W_SD + i];
  for (int i = t; i < EF * NF; i += 256) sWnc[i] = wbuf[W_NC + i];
  sWC[t] = wbuf[W_COMB + t];
  if (t < 64) sPB[t] = wbuf[B_SD + t];
  if (t < NF) sbvec[t] = wbuf[B_VEC + t];
  if (t < EF) sBC[t] = wbuf[B_COMB + t];

  int ns0 = nstart[blockIdx.x], ns1 = nstart[blockIdx.x + 1];
  int base = off[ns0], end = off[ns1];
  int cntE = end - base;
  // stage this block's e rows into LDS (coalesced float4)
  {
    const float4* s4 = (const float4*)(e_src + (size_t)base * EF);
    float4* d4 = (float4*)eL;
    for (int i = t; i < cntE * 4; i += 256) d4[i] = s4[i];
  }
  __syncthreads();

  // ---------------- node phase: 2 threads/node over LDS rows ----------------
  int nN = ns1 - ns0;
  int p = t & 1;
  for (int s0 = t >> 1; s0 < nN; s0 += 128) {
    int n = ns0 + s0;
    int a0 = off[n] - base, a1 = off[n + 1] - base;

    // prefetch hpart early (p==0): global latency overlaps LDS sum loop
    float4 hv[8];
    if (p == 0) {
      const float4* hp = (const float4*)(hpart + (size_t)n * NF);
#pragma unroll
      for (int j4 = 0; j4 < 8; ++j4) hv[j4] = hp[j4];
    }

    float s8[8] = {0, 0, 0, 0, 0, 0, 0, 0};
    for (int q = a0; q < a1; ++q) {
      const float4* ep = (const float4*)(eL + q * EF + 8 * p);
      float4 a = ep[0], b = ep[1];
      s8[0] += a.x; s8[1] += a.y; s8[2] += a.z; s8[3] += a.w;
      s8[4] += b.x; s8[5] += b.y; s8[6] += b.z; s8[7] += b.w;
    }

    float z[NF];
    if (p == 0) {
#pragma unroll
      for (int j4 = 0; j4 < 8; ++j4) {
        z[4 * j4] = hv[j4].x; z[4 * j4 + 1] = hv[j4].y;
        z[4 * j4 + 2] = hv[j4].z; z[4 * j4 + 3] = hv[j4].w;
      }
    } else {
      float dg = (float)(a1 - a0);
#pragma unroll
      for (int j = 0; j < NF; ++j) z[j] = dg * sbvec[j];
    }
#pragma unroll
    for (int k = 0; k < 8; ++k) {
      float v = s8[k];
      const float4* wr = (const float4*)(sWnc + (8 * p + k) * NF);
#pragma unroll
      for (int j4 = 0; j4 < 8; ++j4) {
        float4 w = wr[j4];
        z[4 * j4 + 0] = fmaf(v, w.x, z[4 * j4 + 0]);
        z[4 * j4 + 1] = fmaf(v, w.y, z[4 * j4 + 1]);
        z[4 * j4 + 2] = fmaf(v, w.z, z[4 * j4 + 2]);
        z[4 * j4 + 3] = fmaf(v, w.w, z[4 * j4 + 3]);
      }
    }
#pragma unroll
    for (int j = 0; j < NF; ++j) z[j] += __shfl_xor(z[j], 1, 64);
#pragma unroll
    for (int j = 0; j < NF; ++j) z[j] = sigmoidf_(z[j]);

    float pr[NF];
    const float* pb = sPB + p * 32;
#pragma unroll
    for (int j = 0; j < NF; ++j) pr[j] = pb[j];
    const float* wbase = sPRJ + p * 1024;
    for (int k = 0; k < NF; ++k) {
      float v = z[k];
      const float4* wr = (const float4*)(wbase + k * NF);
#pragma unroll
      for (int j4 = 0; j4 < 8; ++j4) {
        float4 w = wr[j4];
        pr[4 * j4 + 0] = fmaf(v, w.x, pr[4 * j4 + 0]);
        pr[4 * j4 + 1] = fmaf(v, w.y, pr[4 * j4 + 1]);
        pr[4 * j4 + 2] = fmaf(v, w.z, pr[4 * j4 + 2]);
        pr[4 * j4 + 3] = fmaf(v, w.w, pr[4 * j4 + 3]);
      }
    }
    if (p == 0) {
      float4* a = (float4*)(Ps_next + (size_t)n * EF);
      a[0] = make_float4(pr[0], pr[1], pr[2], pr[3]);
      a[1] = make_float4(pr[4], pr[5], pr[6], pr[7]);
      a[2] = make_float4(pr[8], pr[9], pr[10], pr[11]);
      a[3] = make_float4(pr[12], pr[13], pr[14], pr[15]);
      float4* b = (float4*)(Pd_next + (size_t)n * EF);
      b[0] = make_float4(pr[16], pr[17], pr[18], pr[19]);
      b[1] = make_float4(pr[20], pr[21], pr[22], pr[23]);
      b[2] = make_float4(pr[24], pr[25], pr[26], pr[27]);
      b[3] = make_float4(pr[28], pr[29], pr[30], pr[31]);
    } else {
      float4* h = (float4*)(hpart + (size_t)n * NF);
#pragma unroll
      for (int j4 = 0; j4 < 8; ++j4)
        h[j4] = make_float4(pr[4 * j4], pr[4 * j4 + 1], pr[4 * j4 + 2], pr[4 * j4 + 3]);
    }
  }

  // ---------------- edge phase: all threads over staged rows ----------------
  for (int idx = t; idx < cntE; idx += 256) {
    int q = base + idx;
    int s = src_s[q], d = dst_s[q];
    const float4* ps = (const float4*)(Ps_cur + (size_t)s * EF);
    const float4* pd = (const float4*)(Pd_cur + (size_t)d * EF);
    float4 pa0 = ps[0], pa1 = ps[1], pa2 = ps[2], pa3 = ps[3];
    float4 pb0 = pd[0], pb1 = pd[1], pb2 = pd[2], pb3 = pd[3];

    float e[EF];
    const float4* el4 = (const float4*)(eL + idx * EF);
#pragma unroll
    for (int k4 = 0; k4 < 4; ++k4) {
      float4 v = el4[k4];
      e[4 * k4] = v.x; e[4 * k4 + 1] = v.y; e[4 * k4 + 2] = v.z; e[4 * k4 + 3] = v.w;
    }
    float z[EF];
    z[0] = sBC[0] + pa0.x + pb0.x;  z[1] = sBC[1] + pa0.y + pb0.y;
    z[2] = sBC[2] + pa0.z + pb0.z;  z[3] = sBC[3] + pa0.w + pb0.w;
    z[4] = sBC[4] + pa1.x + pb1.x;  z[5] = sBC[5] + pa1.y + pb1.y;
    z[6] = sBC[6] + pa1.z + pb1.z;  z[7] = sBC[7] + pa1.w + pb1.w;
    z[8] = sBC[8] + pa2.x + pb2.x;  z[9] = sBC[9] + pa2.y + pb2.y;
    z[10] = sBC[10] + pa2.z + pb2.z; z[11] = sBC[11] + pa2.w + pb2.w;
    z[12] = sBC[12] + pa3.x + pb3.x; z[13] = sBC[13] + pa3.y + pb3.y;
    z[14] = sBC[14] + pa3.z + pb3.z; z[15] = sBC[15] + pa3.w + pb3.w;
#pragma unroll
    for (int k = 0; k < EF; ++k) {
      float v = e[k];
      const float4* wr = (const float4*)(sWC + k * EF);
#pragma unroll
      for (int i4 = 0; i4 < 4; ++i4) {
        float4 w = wr[i4];
        z[4 * i4 + 0] = fmaf(v, w.x, z[4 * i4 + 0]);
        z[4 * i4 + 1] = fmaf(v, w.y, z[4 * i4 + 1]);
        z[4 * i4 + 2] = fmaf(v, w.z, z[4 * i4 + 2]);
        z[4 * i4 + 3] = fmaf(v, w.w, z[4 * i4 + 3]);
      }
    }
    float4* obp = (float4*)(e_dst + (size_t)q * EF);
#pragma unroll
    for (int i4 = 0; i4 < 4; ++i4)
      obp[i4] = make_float4(sigmoidf_(z[4 * i4]), sigmoidf_(z[4 * i4 + 1]),
                            sigmoidf_(z[4 * i4 + 2]), sigmoidf_(z[4 * i4 + 3]));
  }
}

// ---------------------------------------------------------------------------
// final node pass (iter 12): z/sig as above, then out = sig @ Wnf + bnf
// ---------------------------------------------------------------------------
__global__ void __launch_bounds__(256) final_kernel(
    const float* __restrict__ e_buf, const float* __restrict__ hpart,
    const int* __restrict__ off, const float* __restrict__ wbuf,
    float* __restrict__ out) {
  __shared__ float sWnc[EF * NF];
  __shared__ float sbvec[NF];
  __shared__ float sWNF[NF * NC];
  __shared__ float sBNF[NC];
  for (int i = threadIdx.x; i < EF * NF; i += 256) sWnc[i] = wbuf[W_NC + i];
  if (threadIdx.x < NF) sbvec[threadIdx.x] = wbuf[B_VEC + threadIdx.x];
  if (threadIdx.x < NF * NC) sWNF[threadIdx.x] = wbuf[W_NF + threadIdx.x];
  if (threadIdx.x < NC) sBNF[threadIdx.x] = wbuf[B_NF + threadIdx.x];
  __syncthreads();
  int gid = blockIdx.x * 256 + threadIdx.x;
  int n = gid >> 1, p = gid & 1;
  if (n >= N_NODES) return;
  int o0 = off[n], o1 = off[n + 1];

  float s8[8] = {0, 0, 0, 0, 0, 0, 0, 0};
  for (int q = o0; q < o1; ++q) {
    const float4* ep = (const float4*)(e_buf + (size_t)q * EF + 8 * p);
    float4 a = ep[0], b = ep[1];
    s8[0] += a.x; s8[1] += a.y; s8[2] += a.z; s8[3] += a.w;
    s8[4] += b.x; s8[5] += b.y; s8[6] += b.z; s8[7] += b.w;
  }
  float z[NF];
  if (p == 0) {
    const float4* hp = (const float4*)(hpart + (size_t)n * NF);
#pragma unroll
    for (int j4 = 0; j4 < 8; ++j4) {
      float4 v = hp[j4];
      z[4 * j4] = v.x; z[4 * j4 + 1] = v.y; z[4 * j4 + 2] = v.z; z[4 * j4 + 3] = v.w;
    }
  } else {
    float dg = (float)(o1 - o0);
#pragma unroll
    for (int j = 0; j < NF; ++j) z[j] = dg * sbvec[j];
  }
#pragma unroll
  for (int k = 0; k < 8; ++k) {
    float v = s8[k];
    const float4* wr = (const float4*)(sWnc + (8 * p + k) * NF);
#pragma unroll
    for (int j4 = 0; j4 < 8; ++j4) {
      float4 w = wr[j4];
      z[4 * j4 + 0] = fmaf(v, w.x, z[4 * j4 + 0]);
      z[4 * j4 + 1] = fmaf(v, w.y, z[4 * j4 + 1]);
      z[4 * j4 + 2] = fmaf(v, w.z, z[4 * j4 + 2]);
      z[4 * j4 + 3] = fmaf(v, w.w, z[4 * j4 + 3]);
    }
  }
#pragma unroll
  for (int j = 0; j < NF; ++j) z[j] += __shfl_xor(z[j], 1, 64);
#pragma unroll
  for (int j = 0; j < NF; ++j) z[j] = sigmoidf_(z[j]);

  float o[NC];
  float pm = (p == 0) ? 1.0f : 0.0f;
#pragma unroll
  for (int c = 0; c < NC; ++c) o[c] = pm * sBNF[c];
  for (int k = 0; k < 16; ++k) {
    float v = z[16 * p + k];
    const float* wr = sWNF + (16 * p + k) * NC;
#pragma unroll
    for (int c = 0; c < NC; ++c) o[c] = fmaf(v, wr[c], o[c]);
  }
#pragma unroll
  for (int c = 0; c < NC; ++c) o[c] += __shfl_xor(o[c], 1, 64);
  if (p == 0) {
    float4* op = (float4*)(out + (size_t)n * NC);
    op[0] = make_float4(o[0], o[1], o[2], o[3]);
    op[1] = make_float4(o[4], o[5], o[6], o[7]);
  }
}

// ---------------------------------------------------------------------------
extern "C" void kernel_launch(void* const* d_in, const int* in_sizes, int n_in,
                              void* d_out, int out_size, void* d_ws, size_t ws_size,
                              hipStream_t stream) {
  const float* node_feat = (const float*)d_in[0];
  const float* edge_feat = (const float*)d_in[1];
  const int*   src = (const int*)d_in[2];
  const int*   dst = (const int*)d_in[3];
  const float* Wn  = (const float*)d_in[4];
  const float* bn  = (const float*)d_in[5];
  const float* We  = (const float*)d_in[6];
  const float* be  = (const float*)d_in[7];
  const float* Wem = (const float*)d_in[8];
  const float* bem = (const float*)d_in[9];
  const float* Wnm = (const float*)d_in[10];
  const float* bnm = (const float*)d_in[11];
  const float* Wfc = (const float*)d_in[12];
  const float* bfc = (const float*)d_in[13];
  float* out = (float*)d_out;

  float* ws    = (float*)d_ws;
  float* e_b0  = ws;                                   // 3,840,000 f
  float* e_b1  = e_b0 + (size_t)N_EDGES * EF;          // 3,840,000 f
  float* hpart = e_b1 + (size_t)N_EDGES * EF;          //   960,000 f
  float* Ps0   = hpart + (size_t)N_NODES * NF;         //   480,000 f
  float* Pd0   = Ps0 + (size_t)N_NODES * EF;
  float* Ps1   = Pd0 + (size_t)N_NODES * EF;
  float* Pd1   = Ps1 + (size_t)N_NODES * EF;
  float* wbuf  = Pd1 + (size_t)N_NODES * EF;           //     4,096 f
  int* cnt     = (int*)(wbuf + 4096);                  //    30,000 i
  int* off     = cnt + N_NODES;                        //    30,001 i
  int* cursor  = off + N_NODES + 1;                    //    30,000 i
  int* nstart  = cursor + N_NODES;                     //       940 i
  unsigned short* src_s = (unsigned short*)(nstart + NBLK + 2);  // 240,000 u16
  unsigned short* dst_s = src_s + N_EDGES;                       // 240,000 u16
  float* PsA[2] = {Ps0, Ps1};
  float* PdA[2] = {Pd0, Pd1};
  float* EbA[2] = {e_b0, e_b1};

  // --- counting sort of edges by dst + weight folding (fused preamble) ---
  hipMemsetAsync(cnt, 0, (size_t)N_NODES * sizeof(int), stream);
  hist_pre_kernel<<<EB_GRID + 1, 256, 0, stream>>>(
      dst, cnt, Wn, bn, We, be, Wem, bem, Wnm, bnm, Wfc, bfc, wbuf);
  scan_kernel<<<1, 1024, 0, stream>>>(cnt, off, cursor);
  scatter_init_kernel<<<EB_GRID + NB2_GRID + 1, 256, 0, stream>>>(
      edge_feat, src, dst, cursor, src_s, dst_s, e_b0,
      node_feat, wbuf, Ps1, Pd1, hpart, off, nstart);

  // 11 block-centric fused passes (node_i + edge_i share staged e rows).
  for (int i = 1; i <= 11; ++i) {
    fused2_kernel<<<NBLK, 256, 0, stream>>>(
        EbA[(i + 1) & 1], EbA[i & 1], src_s, dst_s,
        PsA[i & 1], PdA[i & 1], hpart, off, nstart, wbuf,
        PsA[(i + 1) & 1], PdA[(i + 1) & 1]);
  }
  // node pass 12 fused with the output head; e-state 11 lives in EbA[1].
  final_kernel<<<NB2_GRID, 256, 0, stream>>>(EbA[1], hpart, off, wbuf, out);
}

// Round 4
// 703.091 us; speedup vs baseline: 1.4697x; 1.4697x over previous
//
#include <hip/hip_runtime.h>

#define N_NODES 30000
#define N_EDGES 240000
#define NF 32
#define EF 16
#define HF 64
#define NC 8

#define EB_GRID  938   // (N_EDGES + 255) / 256
#define NB2_GRID 235   // (2*N_NODES + 255) / 256
#define SAGG_ROWS 160  // node-span capacity per 256-edge chunk (typ ~34)
#define SAGG_STR  17   // padded LDS row stride (bank spread)

// wbuf layout (float offsets)
#define W_COMB 0      // [16][16] We @ Wem[64:128)
#define B_COMB 256    // [16]     bem + be@Wem[64:128)
#define W_NC   272    // [16][32] We @ Wnm[0:64)
#define B_VEC  784    // [32]     be @ Wnm[0:64)
#define W_SD   816    // [32][32] cols 0-15: Wn@Wem[0:64) ; cols 16-31: Wn@Wem[128:192)
#define W_NB   1840   // [32][32] Wn @ Wnm[64:128)
#define B_SD   2864   // [32]     [bn@WemS | bn@WemD]
#define B_NB   2896   // [32]     bnm + bn@Wnm[64:128)
#define W_NF   2928   // [32][8]  Wn @ Wfc
#define B_NF   3184   // [8]      bfc + bn@Wfc

// precompute LDS staging layout (float offsets)
#define LWn   0
#define LWe   2048
#define LWem  3072
#define LWnm  6144
#define LWfc  10240
#define Lbn   10752
#define Lbe   10816
#define Lbem  10880
#define Lbnm  10896
#define Lbfc  10928
#define LTOT  10936

__device__ __forceinline__ float sigmoidf_(float x) {
  return 1.0f / (1.0f + __expf(-x));
}

// ---------------------------------------------------------------------------
// hist (blocks 0..EB-1) + precompute (block EB) — precompute LDS-stages all
// weights with coalesced loads (one latency round) before folding.
// ---------------------------------------------------------------------------
__global__ void __launch_bounds__(256) hist_pre_kernel(
    const int* __restrict__ dst, int* __restrict__ cnt,
    const float* __restrict__ Wn, const float* __restrict__ bn,
    const float* __restrict__ We, const float* __restrict__ be,
    const float* __restrict__ Wem, const float* __restrict__ bem,
    const float* __restrict__ Wnm, const float* __restrict__ bnm,
    const float* __restrict__ Wfc, const float* __restrict__ bfc,
    float* __restrict__ wbuf) {
  __shared__ float sW[LTOT];
  if (blockIdx.x < EB_GRID) {
    int e = blockIdx.x * 256 + threadIdx.x;
    if (e < N_EDGES) atomicAdd(&cnt[dst[e]], 1);
    return;
  }
  int tid = threadIdx.x;
  for (int i = tid; i < 2048; i += 256) sW[LWn + i] = Wn[i];
  for (int i = tid; i < 1024; i += 256) sW[LWe + i] = We[i];
  for (int i = tid; i < 3072; i += 256) sW[LWem + i] = Wem[i];
  for (int i = tid; i < 4096; i += 256) sW[LWnm + i] = Wnm[i];
  for (int i = tid; i < 512; i += 256) sW[LWfc + i] = Wfc[i];
  if (tid < 64) sW[Lbn + tid] = bn[tid];
  if (tid < 64) sW[Lbe + tid] = be[tid];
  if (tid < 16) sW[Lbem + tid] = bem[tid];
  if (tid < 32) sW[Lbnm + tid] = bnm[tid];
  if (tid < 8)  sW[Lbfc + tid] = bfc[tid];
  __syncthreads();
  {  // Wcomb
    int r = tid >> 4, c = tid & 15;
    float acc = 0.f;
    for (int j = 0; j < HF; ++j)
      acc = fmaf(sW[LWe + r * HF + j], sW[LWem + (HF + j) * EF + c], acc);
    wbuf[W_COMB + tid] = acc;
  }
  for (int idx = tid; idx < EF * NF; idx += 256) {  // Wnc
    int r = idx >> 5, c = idx & 31;
    float acc = 0.f;
    for (int j = 0; j < HF; ++j)
      acc = fmaf(sW[LWe + r * HF + j], sW[LWnm + j * NF + c], acc);
    wbuf[W_NC + idx] = acc;
  }
  for (int idx = tid; idx < NF * NF; idx += 256) {  // WSD
    int r = idx >> 5, c = idx & 31;
    float acc = 0.f;
    if (c < EF) {
      for (int j = 0; j < HF; ++j)
        acc = fmaf(sW[LWn + r * HF + j], sW[LWem + j * EF + c], acc);
    } else {
      int cc = c - EF;
      for (int j = 0; j < HF; ++j)
        acc = fmaf(sW[LWn + r * HF + j], sW[LWem + (2 * HF + j) * EF + cc], acc);
    }
    wbuf[W_SD + idx] = acc;
  }
  for (int idx = tid; idx < NF * NF; idx += 256) {  // WnB
    int r = idx >> 5, c = idx & 31;
    float acc = 0.f;
    for (int j = 0; j < HF; ++j)
      acc = fmaf(sW[LWn + r * HF + j], sW[LWnm + (HF + j) * NF + c], acc);
    wbuf[W_NB + idx] = acc;
  }
  if (tid < NF * NC) {  // Wnf
    int r = tid >> 3, c = tid & 7;
    float acc = 0.f;
    for (int j = 0; j < HF; ++j)
      acc = fmaf(sW[LWn + r * HF + j], sW[LWfc + j * NC + c], acc);
    wbuf[W_NF + tid] = acc;
  }
  if (tid < EF) {  // bcomb
    float acc = sW[Lbem + tid];
    for (int j = 0; j < HF; ++j)
      acc = fmaf(sW[Lbe + j], sW[LWem + (HF + j) * EF + tid], acc);
    wbuf[B_COMB + tid] = acc;
  }
  if (tid < NF) {  // bvec
    float acc = 0.f;
    for (int j = 0; j < HF; ++j)
      acc = fmaf(sW[Lbe + j], sW[LWnm + j * NF + tid], acc);
    wbuf[B_VEC + tid] = acc;
  }
  if (tid < NF) {  // bSD
    float acc = 0.f;
    if (tid < EF) {
      for (int j = 0; j < HF; ++j)
        acc = fmaf(sW[Lbn + j], sW[LWem + j * EF + tid], acc);
    } else {
      int cc = tid - EF;
      for (int j = 0; j < HF; ++j)
        acc = fmaf(sW[Lbn + j], sW[LWem + (2 * HF + j) * EF + cc], acc);
    }
    wbuf[B_SD + tid] = acc;
  }
  if (tid < NF) {  // bNB
    float acc = sW[Lbnm + tid];
    for (int j = 0; j < HF; ++j)
      acc = fmaf(sW[Lbn + j], sW[LWnm + (HF + j) * NF + tid], acc);
    wbuf[B_NB + tid] = acc;
  }
  if (tid < NC) {  // bnf
    float acc = sW[Lbfc + tid];
    for (int j = 0; j < HF; ++j)
      acc = fmaf(sW[Lbn + j], sW[LWfc + j * NC + tid], acc);
    wbuf[B_NF + tid] = acc;
  }
}

// exclusive scan of cnt[30000] -> off[30001], cursor = copy of off
__global__ void __launch_bounds__(1024) scan_kernel(
    const int* __restrict__ cnt, int* __restrict__ off, int* __restrict__ cursor) {
  __shared__ int part[1024];
  int t = threadIdx.x;
  const int CH = (N_NODES + 1023) / 1024;   // 30
  int base = t * CH;
  int lc[CH];
  int sum = 0;
  for (int i = 0; i < CH; ++i) {
    int idx = base + i;
    lc[i] = (idx < N_NODES) ? cnt[idx] : 0;
    sum += lc[i];
  }
  part[t] = sum;
  __syncthreads();
  for (int ofs = 1; ofs < 1024; ofs <<= 1) {
    int v = (t >= ofs) ? part[t - ofs] : 0;
    __syncthreads();
    part[t] += v;
    __syncthreads();
  }
  int run = (t == 0) ? 0 : part[t - 1];
  for (int i = 0; i < CH; ++i) {
    int idx = base + i;
    if (idx < N_NODES) {
      off[idx] = run;
      cursor[idx] = run;
      run += lc[i];
    }
  }
  if (t == 1023) off[N_NODES] = part[1023];
}

// ---------------------------------------------------------------------------
// scatter (blocks 0..EB-1) + init_proj (blocks EB..EB+NB2-1).
// ---------------------------------------------------------------------------
__global__ void __launch_bounds__(256) scatter_init_kernel(
    const float* __restrict__ edge_feat, const int* __restrict__ src,
    const int* __restrict__ dst, int* __restrict__ cursor,
    unsigned short* __restrict__ src_s, unsigned short* __restrict__ dst_s,
    float* __restrict__ e_buf,
    const float* __restrict__ node_feat, const float* __restrict__ wbuf,
    float* __restrict__ Ps, float* __restrict__ Pd, float* __restrict__ hpart) {
  if (blockIdx.x < EB_GRID) {
    int e = blockIdx.x * 256 + threadIdx.x;
    if (e >= N_EDGES) return;
    int d = dst[e];
    int pos = atomicAdd(&cursor[d], 1);
    src_s[pos] = (unsigned short)src[e];
    dst_s[pos] = (unsigned short)d;
    const float4* ep = (const float4*)(edge_feat + (size_t)e * EF);
    float4* op = (float4*)(e_buf + (size_t)pos * EF);
    op[0] = ep[0]; op[1] = ep[1]; op[2] = ep[2]; op[3] = ep[3];
    return;
  }
  __shared__ float sPRJ[2048];
  __shared__ float sPB[64];
  for (int i = threadIdx.x; i < 2048; i += 256) sPRJ[i] = wbuf[W_SD + i];
  if (threadIdx.x < 64) sPB[threadIdx.x] = wbuf[B_SD + threadIdx.x];
  __syncthreads();
  int gid = (blockIdx.x - EB_GRID) * 256 + threadIdx.x;
  int n = gid >> 1, p = gid & 1;
  if (n >= N_NODES) return;
  float x[NF];
  const float4* xp = (const float4*)(node_feat + (size_t)n * NF);
#pragma unroll
  for (int k4 = 0; k4 < 8; ++k4) {
    float4 v = xp[k4];
    x[4 * k4] = v.x; x[4 * k4 + 1] = v.y; x[4 * k4 + 2] = v.z; x[4 * k4 + 3] = v.w;
  }
  float pr[NF];
  const float* pb = sPB + p * 32;
#pragma unroll
  for (int j = 0; j < NF; ++j) pr[j] = pb[j];
  const float* wbase = sPRJ + p * 1024;
  for (int k = 0; k < NF; ++k) {
    float v = x[k];
    const float4* wr = (const float4*)(wbase + k * NF);
#pragma unroll
    for (int j4 = 0; j4 < 8; ++j4) {
      float4 w = wr[j4];
      pr[4 * j4 + 0] = fmaf(v, w.x, pr[4 * j4 + 0]);
      pr[4 * j4 + 1] = fmaf(v, w.y, pr[4 * j4 + 1]);
      pr[4 * j4 + 2] = fmaf(v, w.z, pr[4 * j4 + 2]);
      pr[4 * j4 + 3] = fmaf(v, w.w, pr[4 * j4 + 3]);
    }
  }
  if (p == 0) {
    float4* a = (float4*)(Ps + (size_t)n * EF);
    a[0] = make_float4(pr[0], pr[1], pr[2], pr[3]);
    a[1] = make_float4(pr[4], pr[5], pr[6], pr[7]);
    a[2] = make_float4(pr[8], pr[9], pr[10], pr[11]);
    a[3] = make_float4(pr[12], pr[13], pr[14], pr[15]);
    float4* b = (float4*)(Pd + (size_t)n * EF);
    b[0] = make_float4(pr[16], pr[17], pr[18], pr[19]);
    b[1] = make_float4(pr[20], pr[21], pr[22], pr[23]);
    b[2] = make_float4(pr[24], pr[25], pr[26], pr[27]);
    b[3] = make_float4(pr[28], pr[29], pr[30], pr[31]);
  } else {
    float4* h = (float4*)(hpart + (size_t)n * NF);
#pragma unroll
    for (int j4 = 0; j4 < 8; ++j4)
      h[j4] = make_float4(pr[4 * j4], pr[4 * j4 + 1], pr[4 * j4 + 2], pr[4 * j4 + 3]);
  }
}

// ---------------------------------------------------------------------------
// one-time agg0 = segsum(initial sorted e rows); 2 threads/node, unrolled x2.
// ---------------------------------------------------------------------------
__global__ void __launch_bounds__(256) agg0_kernel(
    const float* __restrict__ e_buf, const int* __restrict__ off,
    float* __restrict__ agg0) {
  int gid = blockIdx.x * 256 + threadIdx.x;
  int n = gid >> 1, p = gid & 1;
  if (n >= N_NODES) return;
  int o0 = off[n], o1 = off[n + 1];
  float4 sA = make_float4(0.f, 0.f, 0.f, 0.f);
  float4 sB = make_float4(0.f, 0.f, 0.f, 0.f);
  const float* ebase = e_buf + 8 * p;
  int q = o0;
  for (; q + 1 < o1; q += 2) {
    const float4* e0 = (const float4*)(ebase + (size_t)q * EF);
    const float4* e1 = (const float4*)(ebase + (size_t)(q + 1) * EF);
    float4 a = e0[0], b = e0[1], c = e1[0], d = e1[1];
    sA.x += a.x; sA.y += a.y; sA.z += a.z; sA.w += a.w;
    sB.x += b.x; sB.y += b.y; sB.z += b.z; sB.w += b.w;
    sA.x += c.x; sA.y += c.y; sA.z += c.z; sA.w += c.w;
    sB.x += d.x; sB.y += d.y; sB.z += d.z; sB.w += d.w;
  }
  if (q < o1) {
    const float4* e0 = (const float4*)(ebase + (size_t)q * EF);
    float4 a = e0[0], b = e0[1];
    sA.x += a.x; sA.y += a.y; sA.z += a.z; sA.w += a.w;
    sB.x += b.x; sB.y += b.y; sB.z += b.z; sB.w += b.w;
  }
  float4* ap = (float4*)(agg0 + (size_t)n * EF + 8 * p);
  ap[0] = sA; ap[1] = sB;
}

// ---------------------------------------------------------------------------
// fused pass i: node blocks [0, NB2) + edge blocks [NB2, NB2+EB).
// node: z = hpart|deg*bvec + aggR[n]@Wnc ; sig ; projections -> Ps/Pd/hpart.
//       Zeroes aggR[n] after reading (prepares it for edge_{i+1}).
// edge: e' = sigmoid(bcomb + e@Wcomb + Ps[src] + Pd[dst]) -> e_dst, AND
//       block-local LDS segment-sum of e' rows (dst-sorted chunk) flushed to
//       aggW: interior nodes plain store, chunk-boundary nodes atomicAdd.
// aggR = G[(i+1)&1] (zeroed after read), aggW = G[i&1] (pre-zeroed).
// ---------------------------------------------------------------------------
__global__ void __launch_bounds__(256) fused3_kernel(
    const float* __restrict__ e_src, float* __restrict__ e_dst,
    const unsigned short* __restrict__ src_s, const unsigned short* __restrict__ dst_s,
    const float* __restrict__ Ps_cur, const float* __restrict__ Pd_cur,
    float* __restrict__ hpart, const int* __restrict__ off,
    const float* __restrict__ wbuf,
    float* __restrict__ Ps_next, float* __restrict__ Pd_next,
    float* __restrict__ aggR, float* __restrict__ aggW) {
  int t = threadIdx.x;
  if (blockIdx.x >= NB2_GRID) {
    // ---------------- edge body ----------------
    __shared__ float sWC[EF * EF];
    __shared__ float sBC[EF];
    __shared__ float sAgg[SAGG_ROWS * SAGG_STR];
    __shared__ int sInfo[2];
    int b = blockIdx.x - NB2_GRID;
    int base = b * 256;
    int end = base + 256; if (end > N_EDGES) end = N_EDGES;
    sWC[t] = wbuf[W_COMB + t];
    if (t < EF) sBC[t] = wbuf[B_COMB + t];
    if (t == 0) { sInfo[0] = dst_s[base]; sInfo[1] = dst_s[end - 1]; }
    for (int i = t; i < SAGG_ROWS * SAGG_STR; i += 256) sAgg[i] = 0.f;
    __syncthreads();
    int d_first = sInfo[0];
    int span = sInfo[1] - d_first + 1;
    bool ok = (span <= SAGG_ROWS);
    int q = base + t;
    if (q < end) {
      int s = src_s[q], d = dst_s[q];
      float e[EF];
      const float4* ebp = (const float4*)(e_src + (size_t)q * EF);
#pragma unroll
      for (int k4 = 0; k4 < 4; ++k4) {
        float4 v = ebp[k4];
        e[4 * k4] = v.x; e[4 * k4 + 1] = v.y; e[4 * k4 + 2] = v.z; e[4 * k4 + 3] = v.w;
      }
      const float4* ps = (const float4*)(Ps_cur + (size_t)s * EF);
      const float4* pd = (const float4*)(Pd_cur + (size_t)d * EF);
      float z[EF];
#pragma unroll
      for (int i4 = 0; i4 < 4; ++i4) {
        float4 a = ps[i4], bb = pd[i4];
        z[4 * i4 + 0] = sBC[4 * i4 + 0] + a.x + bb.x;
        z[4 * i4 + 1] = sBC[4 * i4 + 1] + a.y + bb.y;
        z[4 * i4 + 2] = sBC[4 * i4 + 2] + a.z + bb.z;
        z[4 * i4 + 3] = sBC[4 * i4 + 3] + a.w + bb.w;
      }
#pragma unroll
      for (int k = 0; k < EF; ++k) {
        float v = e[k];
        const float4* wr = (const float4*)(sWC + k * EF);
#pragma unroll
        for (int i4 = 0; i4 < 4; ++i4) {
          float4 w = wr[i4];
          z[4 * i4 + 0] = fmaf(v, w.x, z[4 * i4 + 0]);
          z[4 * i4 + 1] = fmaf(v, w.y, z[4 * i4 + 1]);
          z[4 * i4 + 2] = fmaf(v, w.z, z[4 * i4 + 2]);
          z[4 * i4 + 3] = fmaf(v, w.w, z[4 * i4 + 3]);
        }
      }
#pragma unroll
      for (int i = 0; i < EF; ++i) z[i] = sigmoidf_(z[i]);
      float4* obp = (float4*)(e_dst + (size_t)q * EF);
#pragma unroll
      for (int i4 = 0; i4 < 4; ++i4)
        obp[i4] = make_float4(z[4 * i4], z[4 * i4 + 1], z[4 * i4 + 2], z[4 * i4 + 3]);
      // accumulate e' into block-local segment sums
      if (ok) {
        float* row = sAgg + (d - d_first) * SAGG_STR;
#pragma unroll
        for (int j = 0; j < EF; ++j) atomicAdd(&row[j], z[j]);
      } else {  // pathological span: direct global atomics (aggW pre-zeroed)
        float* grow = aggW + (size_t)d * EF;
#pragma unroll
        for (int j = 0; j < EF; ++j) atomicAdd(&grow[j], z[j]);
      }
    }
    __syncthreads();
    if (ok) {
      for (int r = t; r < span; r += 256) {
        int dd = d_first + r;
        int lo = off[dd], hi = off[dd + 1];
        const float* srow = sAgg + r * SAGG_STR;
        float* grow = aggW + (size_t)dd * EF;
        if (lo >= base && hi <= end) {
          float4* g4 = (float4*)grow;
          g4[0] = make_float4(srow[0], srow[1], srow[2], srow[3]);
          g4[1] = make_float4(srow[4], srow[5], srow[6], srow[7]);
          g4[2] = make_float4(srow[8], srow[9], srow[10], srow[11]);
          g4[3] = make_float4(srow[12], srow[13], srow[14], srow[15]);
        } else {
#pragma unroll
          for (int j = 0; j < EF; ++j) atomicAdd(&grow[j], srow[j]);
        }
      }
    }
    return;
  }
  // ---------------- node body (2 threads/node, agg-fed) ----------------
  __shared__ float sWnc[EF * NF];
  __shared__ float sbvec[NF];
  __shared__ float sPRJ[2048];
  __shared__ float sPB[64];
  for (int i = t; i < 2048; i += 256) sPRJ[i] = wbuf[W_SD + i];
  for (int i = t; i < EF * NF; i += 256) sWnc[i] = wbuf[W_NC + i];
  if (t < 64) sPB[t] = wbuf[B_SD + t];
  if (t < NF) sbvec[t] = wbuf[B_VEC + t];
  __syncthreads();
  int gid = blockIdx.x * 256 + t;
  int n = gid >> 1, p = gid & 1;
  if (n >= N_NODES) return;
  int o0 = off[n], o1 = off[n + 1];

  float* ar = aggR + (size_t)n * EF + 8 * p;
  float4 a0 = ((const float4*)ar)[0];
  float4 a1 = ((const float4*)ar)[1];
  ((float4*)ar)[0] = make_float4(0.f, 0.f, 0.f, 0.f);   // zero for edge_{i+1}
  ((float4*)ar)[1] = make_float4(0.f, 0.f, 0.f, 0.f);
  float s8[8] = {a0.x, a0.y, a0.z, a0.w, a1.x, a1.y, a1.z, a1.w};

  float z[NF];
  if (p == 0) {
    const float4* hp = (const float4*)(hpart + (size_t)n * NF);
#pragma unroll
    for (int j4 = 0; j4 < 8; ++j4) {
      float4 v = hp[j4];
      z[4 * j4] = v.x; z[4 * j4 + 1] = v.y; z[4 * j4 + 2] = v.z; z[4 * j4 + 3] = v.w;
    }
  } else {
    float dg = (float)(o1 - o0);
#pragma unroll
    for (int j = 0; j < NF; ++j) z[j] = dg * sbvec[j];
  }
#pragma unroll
  for (int k = 0; k < 8; ++k) {
    float v = s8[k];
    const float4* wr = (const float4*)(sWnc + (8 * p + k) * NF);
#pragma unroll
    for (int j4 = 0; j4 < 8; ++j4) {
      float4 w = wr[j4];
      z[4 * j4 + 0] = fmaf(v, w.x, z[4 * j4 + 0]);
      z[4 * j4 + 1] = fmaf(v, w.y, z[4 * j4 + 1]);
      z[4 * j4 + 2] = fmaf(v, w.z, z[4 * j4 + 2]);
      z[4 * j4 + 3] = fmaf(v, w.w, z[4 * j4 + 3]);
    }
  }
#pragma unroll
  for (int j = 0; j < NF; ++j) z[j] += __shfl_xor(z[j], 1, 64);
#pragma unroll
  for (int j = 0; j < NF; ++j) z[j] = sigmoidf_(z[j]);

  float pr[NF];
  const float* pb = sPB + p * 32;
#pragma unroll
  for (int j = 0; j < NF; ++j) pr[j] = pb[j];
  const float* wbase = sPRJ + p * 1024;
  for (int k = 0; k < NF; ++k) {
    float v = z[k];
    const float4* wr = (const float4*)(wbase + k * NF);
#pragma unroll
    for (int j4 = 0; j4 < 8; ++j4) {
      float4 w = wr[j4];
      pr[4 * j4 + 0] = fmaf(v, w.x, pr[4 * j4 + 0]);
      pr[4 * j4 + 1] = fmaf(v, w.y, pr[4 * j4 + 1]);
      pr[4 * j4 + 2] = fmaf(v, w.z, pr[4 * j4 + 2]);
      pr[4 * j4 + 3] = fmaf(v, w.w, pr[4 * j4 + 3]);
    }
  }
  if (p == 0) {
    float4* a = (float4*)(Ps_next + (size_t)n * EF);
    a[0] = make_float4(pr[0], pr[1], pr[2], pr[3]);
    a[1] = make_float4(pr[4], pr[5], pr[6], pr[7]);
    a[2] = make_float4(pr[8], pr[9], pr[10], pr[11]);
    a[3] = make_float4(pr[12], pr[13], pr[14], pr[15]);
    float4* b = (float4*)(Pd_next + (size_t)n * EF);
    b[0] = make_float4(pr[16], pr[17], pr[18], pr[19]);
    b[1] = make_float4(pr[20], pr[21], pr[22], pr[23]);
    b[2] = make_float4(pr[24], pr[25], pr[26], pr[27]);
    b[3] = make_float4(pr[28], pr[29], pr[30], pr[31]);
  } else {
    float4* h = (float4*)(hpart + (size_t)n * NF);
#pragma unroll
    for (int j4 = 0; j4 < 8; ++j4)
      h[j4] = make_float4(pr[4 * j4], pr[4 * j4 + 1], pr[4 * j4 + 2], pr[4 * j4 + 3]);
  }
}

// ---------------------------------------------------------------------------
// final node pass (iter 12), agg-fed: z/sig as above, then out = sig@Wnf+bnf
// ---------------------------------------------------------------------------
__global__ void __launch_bounds__(256) final_kernel(
    const float* __restrict__ aggR, const float* __restrict__ hpart,
    const int* __restrict__ off, const float* __restrict__ wbuf,
    float* __restrict__ out) {
  __shared__ float sWnc[EF * NF];
  __shared__ float sbvec[NF];
  __shared__ float sWNF[NF * NC];
  __shared__ float sBNF[NC];
  for (int i = threadIdx.x; i < EF * NF; i += 256) sWnc[i] = wbuf[W_NC + i];
  if (threadIdx.x < NF) sbvec[threadIdx.x] = wbuf[B_VEC + threadIdx.x];
  if (threadIdx.x < NF * NC) sWNF[threadIdx.x] = wbuf[W_NF + threadIdx.x];
  if (threadIdx.x < NC) sBNF[threadIdx.x] = wbuf[B_NF + threadIdx.x];
  __syncthreads();
  int gid = blockIdx.x * 256 + threadIdx.x;
  int n = gid >> 1, p = gid & 1;
  if (n >= N_NODES) return;
  int o0 = off[n], o1 = off[n + 1];

  const float4* ap = (const float4*)(aggR + (size_t)n * EF + 8 * p);
  float4 a0 = ap[0], a1 = ap[1];
  float s8[8] = {a0.x, a0.y, a0.z, a0.w, a1.x, a1.y, a1.z, a1.w};

  float z[NF];
  if (p == 0) {
    const float4* hp = (const float4*)(hpart + (size_t)n * NF);
#pragma unroll
    for (int j4 = 0; j4 < 8; ++j4) {
      float4 v = hp[j4];
      z[4 * j4] = v.x; z[4 * j4 + 1] = v.y; z[4 * j4 + 2] = v.z; z[4 * j4 + 3] = v.w;
    }
  } else {
    float dg = (float)(o1 - o0);
#pragma unroll
    for (int j = 0; j < NF; ++j) z[j] = dg * sbvec[j];
  }
#pragma unroll
  for (int k = 0; k < 8; ++k) {
    float v = s8[k];
    const float4* wr = (const float4*)(sWnc + (8 * p + k) * NF);
#pragma unroll
    for (int j4 = 0; j4 < 8; ++j4) {
      float4 w = wr[j4];
      z[4 * j4 + 0] = fmaf(v, w.x, z[4 * j4 + 0]);
      z[4 * j4 + 1] = fmaf(v, w.y, z[4 * j4 + 1]);
      z[4 * j4 + 2] = fmaf(v, w.z, z[4 * j4 + 2]);
      z[4 * j4 + 3] = fmaf(v, w.w, z[4 * j4 + 3]);
    }
  }
#pragma unroll
  for (int j = 0; j < NF; ++j) z[j] += __shfl_xor(z[j], 1, 64);
#pragma unroll
  for (int j = 0; j < NF; ++j) z[j] = sigmoidf_(z[j]);

  float o[NC];
  float pm = (p == 0) ? 1.0f : 0.0f;
#pragma unroll
  for (int c = 0; c < NC; ++c) o[c] = pm * sBNF[c];
  for (int k = 0; k < 16; ++k) {
    float v = z[16 * p + k];
    const float* wr = sWNF + (16 * p + k) * NC;
#pragma unroll
    for (int c = 0; c < NC; ++c) o[c] = fmaf(v, wr[c], o[c]);
  }
#pragma unroll
  for (int c = 0; c < NC; ++c) o[c] += __shfl_xor(o[c], 1, 64);
  if (p == 0) {
    float4* op = (float4*)(out + (size_t)n * NC);
    op[0] = make_float4(o[0], o[1], o[2], o[3]);
    op[1] = make_float4(o[4], o[5], o[6], o[7]);
  }
}

// ---------------------------------------------------------------------------
extern "C" void kernel_launch(void* const* d_in, const int* in_sizes, int n_in,
                              void* d_out, int out_size, void* d_ws, size_t ws_size,
                              hipStream_t stream) {
  const float* node_feat = (const float*)d_in[0];
  const float* edge_feat = (const float*)d_in[1];
  const int*   src = (const int*)d_in[2];
  const int*   dst = (const int*)d_in[3];
  const float* Wn  = (const float*)d_in[4];
  const float* bn  = (const float*)d_in[5];
  const float* We  = (const float*)d_in[6];
  const float* be  = (const float*)d_in[7];
  const float* Wem = (const float*)d_in[8];
  const float* bem = (const float*)d_in[9];
  const float* Wnm = (const float*)d_in[10];
  const float* bnm = (const float*)d_in[11];
  const float* Wfc = (const float*)d_in[12];
  const float* bfc = (const float*)d_in[13];
  float* out = (float*)d_out;

  float* ws    = (float*)d_ws;
  float* e_b0  = ws;                                   // 3,840,000 f
  float* e_b1  = e_b0 + (size_t)N_EDGES * EF;          // 3,840,000 f
  float* hpart = e_b1 + (size_t)N_EDGES * EF;          //   960,000 f
  float* Ps0   = hpart + (size_t)N_NODES * NF;         //   480,000 f
  float* Pd0   = Ps0 + (size_t)N_NODES * EF;
  float* Ps1   = Pd0 + (size_t)N_NODES * EF;
  float* Pd1   = Ps1 + (size_t)N_NODES * EF;
  float* G0    = Pd1 + (size_t)N_NODES * EF;           //   480,000 f
  float* G1    = G0 + (size_t)N_NODES * EF;            //   480,000 f
  float* wbuf  = G1 + (size_t)N_NODES * EF;            //     4,096 f
  int* cnt     = (int*)(wbuf + 4096);                  //    30,000 i
  int* off     = cnt + N_NODES;                        //    30,001 i
  int* cursor  = off + N_NODES + 1;                    //    30,000 i
  unsigned short* src_s = (unsigned short*)(cursor + N_NODES);  // 240,000 u16
  unsigned short* dst_s = src_s + N_EDGES;                      // 240,000 u16
  float* PsA[2] = {Ps0, Ps1};
  float* PdA[2] = {Pd0, Pd1};
  float* EbA[2] = {e_b0, e_b1};
  float* GA[2]  = {G0, G1};

  // --- preamble: counting sort + weight folding; zero both agg buffers ---
  hipMemsetAsync(cnt, 0, (size_t)N_NODES * sizeof(int), stream);
  hipMemsetAsync(G0, 0, (size_t)2 * N_NODES * EF * sizeof(float), stream);
  hist_pre_kernel<<<EB_GRID + 1, 256, 0, stream>>>(
      dst, cnt, Wn, bn, We, be, Wem, bem, Wnm, bnm, Wfc, bfc, wbuf);
  scan_kernel<<<1, 1024, 0, stream>>>(cnt, off, cursor);
  scatter_init_kernel<<<EB_GRID + NB2_GRID, 256, 0, stream>>>(
      edge_feat, src, dst, cursor, src_s, dst_s, e_b0,
      node_feat, wbuf, Ps1, Pd1, hpart);
  // one-time gather: agg0 = segsum(initial sorted e rows) -> G0
  agg0_kernel<<<NB2_GRID, 256, 0, stream>>>(e_b0, off, G0);

  // 11 fused (node_i || edge_i) passes.
  // node_i reads GA[(i+1)&1] (then zeroes it); edge_i writes GA[i&1].
  // e double-buffer: both read EbA[(i+1)&1], edge writes EbA[i&1].
  // P ping-pong: edge_i reads P[i&1]; node_i writes P[(i+1)&1].
  for (int i = 1; i <= 11; ++i) {
    fused3_kernel<<<NB2_GRID + EB_GRID, 256, 0, stream>>>(
        EbA[(i + 1) & 1], EbA[i & 1], src_s, dst_s,
        PsA[i & 1], PdA[i & 1], hpart, off, wbuf,
        PsA[(i + 1) & 1], PdA[(i + 1) & 1],
        GA[(i + 1) & 1], GA[i & 1]);
  }
  // node pass 12 + output head; edge_11 wrote agg into GA[1].
  final_kernel<<<NB2_GRID, 256, 0, stream>>>(GA[1], hpart, off, wbuf, out);
}

// Round 5
// 425.144 us; speedup vs baseline: 2.4305x; 1.6538x over previous
//
#include <hip/hip_runtime.h>

#define N_NODES 30000
#define N_EDGES 240000
#define NF 32
#define EF 16
#define HF 64
#define NC 8

#define EB_GRID  938   // (N_EDGES + 255) / 256
#define NB2_GRID 235   // (2*N_NODES + 255) / 256
#define ZSTR     17    // sZ row stride (odd -> free 2-way bank aliasing)

// wbuf layout (float offsets)
#define W_COMB 0      // [16][16] We @ Wem[64:128)
#define B_COMB 256    // [16]     bem + be@Wem[64:128)
#define W_NC   272    // [16][32] We @ Wnm[0:64)
#define B_VEC  784    // [32]     be @ Wnm[0:64)
#define W_SD   816    // [32][32] cols 0-15: Wn@Wem[0:64) ; cols 16-31: Wn@Wem[128:192)
#define W_NB   1840   // [32][32] Wn @ Wnm[64:128)
#define B_SD   2864   // [32]     [bn@WemS | bn@WemD]
#define B_NB   2896   // [32]     bnm + bn@Wnm[64:128)
#define W_NF   2928   // [32][8]  Wn @ Wfc
#define B_NF   3184   // [8]      bfc + bn@Wfc

// precompute LDS staging layout (float offsets)
#define LWn   0
#define LWe   2048
#define LWem  3072
#define LWnm  6144
#define LWfc  10240
#define Lbn   10752
#define Lbe   10816
#define Lbem  10880
#define Lbnm  10896
#define Lbfc  10928
#define LTOT  10936

__device__ __forceinline__ float sigmoidf_(float x) {
  return 1.0f / (1.0f + __expf(-x));
}

// ---------------------------------------------------------------------------
// hist (blocks 0..EB-1) + precompute (block EB) — precompute LDS-stages all
// weights with coalesced loads (one latency round) before folding.
// ---------------------------------------------------------------------------
__global__ void __launch_bounds__(256) hist_pre_kernel(
    const int* __restrict__ dst, int* __restrict__ cnt,
    const float* __restrict__ Wn, const float* __restrict__ bn,
    const float* __restrict__ We, const float* __restrict__ be,
    const float* __restrict__ Wem, const float* __restrict__ bem,
    const float* __restrict__ Wnm, const float* __restrict__ bnm,
    const float* __restrict__ Wfc, const float* __restrict__ bfc,
    float* __restrict__ wbuf) {
  __shared__ float sW[LTOT];
  if (blockIdx.x < EB_GRID) {
    int e = blockIdx.x * 256 + threadIdx.x;
    if (e < N_EDGES) atomicAdd(&cnt[dst[e]], 1);
    return;
  }
  int tid = threadIdx.x;
  for (int i = tid; i < 2048; i += 256) sW[LWn + i] = Wn[i];
  for (int i = tid; i < 1024; i += 256) sW[LWe + i] = We[i];
  for (int i = tid; i < 3072; i += 256) sW[LWem + i] = Wem[i];
  for (int i = tid; i < 4096; i += 256) sW[LWnm + i] = Wnm[i];
  for (int i = tid; i < 512; i += 256) sW[LWfc + i] = Wfc[i];
  if (tid < 64) sW[Lbn + tid] = bn[tid];
  if (tid < 64) sW[Lbe + tid] = be[tid];
  if (tid < 16) sW[Lbem + tid] = bem[tid];
  if (tid < 32) sW[Lbnm + tid] = bnm[tid];
  if (tid < 8)  sW[Lbfc + tid] = bfc[tid];
  __syncthreads();
  {  // Wcomb
    int r = tid >> 4, c = tid & 15;
    float acc = 0.f;
    for (int j = 0; j < HF; ++j)
      acc = fmaf(sW[LWe + r * HF + j], sW[LWem + (HF + j) * EF + c], acc);
    wbuf[W_COMB + tid] = acc;
  }
  for (int idx = tid; idx < EF * NF; idx += 256) {  // Wnc
    int r = idx >> 5, c = idx & 31;
    float acc = 0.f;
    for (int j = 0; j < HF; ++j)
      acc = fmaf(sW[LWe + r * HF + j], sW[LWnm + j * NF + c], acc);
    wbuf[W_NC + idx] = acc;
  }
  for (int idx = tid; idx < NF * NF; idx += 256) {  // WSD
    int r = idx >> 5, c = idx & 31;
    float acc = 0.f;
    if (c < EF) {
      for (int j = 0; j < HF; ++j)
        acc = fmaf(sW[LWn + r * HF + j], sW[LWem + j * EF + c], acc);
    } else {
      int cc = c - EF;
      for (int j = 0; j < HF; ++j)
        acc = fmaf(sW[LWn + r * HF + j], sW[LWem + (2 * HF + j) * EF + cc], acc);
    }
    wbuf[W_SD + idx] = acc;
  }
  for (int idx = tid; idx < NF * NF; idx += 256) {  // WnB
    int r = idx >> 5, c = idx & 31;
    float acc = 0.f;
    for (int j = 0; j < HF; ++j)
      acc = fmaf(sW[LWn + r * HF + j], sW[LWnm + (HF + j) * NF + c], acc);
    wbuf[W_NB + idx] = acc;
  }
  if (tid < NF * NC) {  // Wnf
    int r = tid >> 3, c = tid & 7;
    float acc = 0.f;
    for (int j = 0; j < HF; ++j)
      acc = fmaf(sW[LWn + r * HF + j], sW[LWfc + j * NC + c], acc);
    wbuf[W_NF + tid] = acc;
  }
  if (tid < EF) {  // bcomb
    float acc = sW[Lbem + tid];
    for (int j = 0; j < HF; ++j)
      acc = fmaf(sW[Lbe + j], sW[LWem + (HF + j) * EF + tid], acc);
    wbuf[B_COMB + tid] = acc;
  }
  if (tid < NF) {  // bvec
    float acc = 0.f;
    for (int j = 0; j < HF; ++j)
      acc = fmaf(sW[Lbe + j], sW[LWnm + j * NF + tid], acc);
    wbuf[B_VEC + tid] = acc;
  }
  if (tid < NF) {  // bSD
    float acc = 0.f;
    if (tid < EF) {
      for (int j = 0; j < HF; ++j)
        acc = fmaf(sW[Lbn + j], sW[LWem + j * EF + tid], acc);
    } else {
      int cc = tid - EF;
      for (int j = 0; j < HF; ++j)
        acc = fmaf(sW[Lbn + j], sW[LWem + (2 * HF + j) * EF + cc], acc);
    }
    wbuf[B_SD + tid] = acc;
  }
  if (tid < NF) {  // bNB
    float acc = sW[Lbnm + tid];
    for (int j = 0; j < HF; ++j)
      acc = fmaf(sW[Lbn + j], sW[LWnm + (HF + j) * NF + tid], acc);
    wbuf[B_NB + tid] = acc;
  }
  if (tid < NC) {  // bnf
    float acc = sW[Lbfc + tid];
    for (int j = 0; j < HF; ++j)
      acc = fmaf(sW[Lbn + j], sW[LWfc + j * NC + tid], acc);
    wbuf[B_NF + tid] = acc;
  }
}

// exclusive scan of cnt[30000] -> off[30001], cursor = copy of off
__global__ void __launch_bounds__(1024) scan_kernel(
    const int* __restrict__ cnt, int* __restrict__ off, int* __restrict__ cursor) {
  __shared__ int part[1024];
  int t = threadIdx.x;
  const int CH = (N_NODES + 1023) / 1024;   // 30
  int base = t * CH;
  int lc[CH];
  int sum = 0;
  for (int i = 0; i < CH; ++i) {
    int idx = base + i;
    lc[i] = (idx < N_NODES) ? cnt[idx] : 0;
    sum += lc[i];
  }
  part[t] = sum;
  __syncthreads();
  for (int ofs = 1; ofs < 1024; ofs <<= 1) {
    int v = (t >= ofs) ? part[t - ofs] : 0;
    __syncthreads();
    part[t] += v;
    __syncthreads();
  }
  int run = (t == 0) ? 0 : part[t - 1];
  for (int i = 0; i < CH; ++i) {
    int idx = base + i;
    if (idx < N_NODES) {
      off[idx] = run;
      cursor[idx] = run;
      run += lc[i];
    }
  }
  if (t == 1023) off[N_NODES] = part[1023];
}

// ---------------------------------------------------------------------------
// scatter (blocks 0..EB-1) + init_proj (blocks EB..EB+NB2-1).
// ---------------------------------------------------------------------------
__global__ void __launch_bounds__(256) scatter_init_kernel(
    const float* __restrict__ edge_feat, const int* __restrict__ src,
    const int* __restrict__ dst, int* __restrict__ cursor,
    unsigned short* __restrict__ src_s, unsigned short* __restrict__ dst_s,
    float* __restrict__ e_buf,
    const float* __restrict__ node_feat, const float* __restrict__ wbuf,
    float* __restrict__ Ps, float* __restrict__ Pd, float* __restrict__ hpart) {
  if (blockIdx.x < EB_GRID) {
    int e = blockIdx.x * 256 + threadIdx.x;
    if (e >= N_EDGES) return;
    int d = dst[e];
    int pos = atomicAdd(&cursor[d], 1);
    src_s[pos] = (unsigned short)src[e];
    dst_s[pos] = (unsigned short)d;
    const float4* ep = (const float4*)(edge_feat + (size_t)e * EF);
    float4* op = (float4*)(e_buf + (size_t)pos * EF);
    op[0] = ep[0]; op[1] = ep[1]; op[2] = ep[2]; op[3] = ep[3];
    return;
  }
  __shared__ float sPRJ[2048];
  __shared__ float sPB[64];
  for (int i = threadIdx.x; i < 2048; i += 256) sPRJ[i] = wbuf[W_SD + i];
  if (threadIdx.x < 64) sPB[threadIdx.x] = wbuf[B_SD + threadIdx.x];
  __syncthreads();
  int gid = (blockIdx.x - EB_GRID) * 256 + threadIdx.x;
  int n = gid >> 1, p = gid & 1;
  if (n >= N_NODES) return;
  float x[NF];
  const float4* xp = (const float4*)(node_feat + (size_t)n * NF);
#pragma unroll
  for (int k4 = 0; k4 < 8; ++k4) {
    float4 v = xp[k4];
    x[4 * k4] = v.x; x[4 * k4 + 1] = v.y; x[4 * k4 + 2] = v.z; x[4 * k4 + 3] = v.w;
  }
  float pr[NF];
  const float* pb = sPB + p * 32;
#pragma unroll
  for (int j = 0; j < NF; ++j) pr[j] = pb[j];
  const float* wbase = sPRJ + p * 1024;
  for (int k = 0; k < NF; ++k) {
    float v = x[k];
    const float4* wr = (const float4*)(wbase + k * NF);
#pragma unroll
    for (int j4 = 0; j4 < 8; ++j4) {
      float4 w = wr[j4];
      pr[4 * j4 + 0] = fmaf(v, w.x, pr[4 * j4 + 0]);
      pr[4 * j4 + 1] = fmaf(v, w.y, pr[4 * j4 + 1]);
      pr[4 * j4 + 2] = fmaf(v, w.z, pr[4 * j4 + 2]);
      pr[4 * j4 + 3] = fmaf(v, w.w, pr[4 * j4 + 3]);
    }
  }
  if (p == 0) {
    float4* a = (float4*)(Ps + (size_t)n * EF);
    a[0] = make_float4(pr[0], pr[1], pr[2], pr[3]);
    a[1] = make_float4(pr[4], pr[5], pr[6], pr[7]);
    a[2] = make_float4(pr[8], pr[9], pr[10], pr[11]);
    a[3] = make_float4(pr[12], pr[13], pr[14], pr[15]);
    float4* b = (float4*)(Pd + (size_t)n * EF);
    b[0] = make_float4(pr[16], pr[17], pr[18], pr[19]);
    b[1] = make_float4(pr[20], pr[21], pr[22], pr[23]);
    b[2] = make_float4(pr[24], pr[25], pr[26], pr[27]);
    b[3] = make_float4(pr[28], pr[29], pr[30], pr[31]);
  } else {
    float4* h = (float4*)(hpart + (size_t)n * NF);
#pragma unroll
    for (int j4 = 0; j4 < 8; ++j4)
      h[j4] = make_float4(pr[4 * j4], pr[4 * j4 + 1], pr[4 * j4 + 2], pr[4 * j4 + 3]);
  }
}

// ---------------------------------------------------------------------------
// one-time agg0 = segsum(initial sorted e rows); 2 threads/node, unrolled x2.
// ---------------------------------------------------------------------------
__global__ void __launch_bounds__(256) agg0_kernel(
    const float* __restrict__ e_buf, const int* __restrict__ off,
    float* __restrict__ agg0) {
  int gid = blockIdx.x * 256 + threadIdx.x;
  int n = gid >> 1, p = gid & 1;
  if (n >= N_NODES) return;
  int o0 = off[n], o1 = off[n + 1];
  float4 sA = make_float4(0.f, 0.f, 0.f, 0.f);
  float4 sB = make_float4(0.f, 0.f, 0.f, 0.f);
  const float* ebase = e_buf + 8 * p;
  int q = o0;
  for (; q + 1 < o1; q += 2) {
    const float4* e0 = (const float4*)(ebase + (size_t)q * EF);
    const float4* e1 = (const float4*)(ebase + (size_t)(q + 1) * EF);
    float4 a = e0[0], b = e0[1], c = e1[0], d = e1[1];
    sA.x += a.x; sA.y += a.y; sA.z += a.z; sA.w += a.w;
    sB.x += b.x; sB.y += b.y; sB.z += b.z; sB.w += b.w;
    sA.x += c.x; sA.y += c.y; sA.z += c.z; sA.w += c.w;
    sB.x += d.x; sB.y += d.y; sB.z += d.z; sB.w += d.w;
  }
  if (q < o1) {
    const float4* e0 = (const float4*)(ebase + (size_t)q * EF);
    float4 a = e0[0], b = e0[1];
    sA.x += a.x; sA.y += a.y; sA.z += a.z; sA.w += a.w;
    sB.x += b.x; sB.y += b.y; sB.z += b.z; sB.w += b.w;
  }
  float4* ap = (float4*)(agg0 + (size_t)n * EF + 8 * p);
  ap[0] = sA; ap[1] = sB;
}

// ---------------------------------------------------------------------------
// fused pass i: node blocks [0, NB2) + edge blocks [NB2, NB2+EB).
// node: z = hpart|deg*bvec + aggR[n]@Wnc ; sig ; projections -> Ps/Pd/hpart.
//       Zeroes aggR[n] after reading (prepares it for edge_{i+1}).
// edge: e' = sigmoid(bcomb + e@Wcomb + Ps[src] + Pd[dst]) -> e_dst AND sZ,
//       then conflict-free two-phase segment reduction from sZ:
//       8 threads/node, 2 features each, serial over the node's LDS rows.
//       Interior nodes: plain store to aggW; boundary nodes: atomicAdd.
// aggR = G[(i+1)&1] (zeroed after read), aggW = G[i&1] (pre-zeroed).
// ---------------------------------------------------------------------------
__global__ void __launch_bounds__(256) fused4_kernel(
    const float* __restrict__ e_src, float* __restrict__ e_dst,
    const unsigned short* __restrict__ src_s, const unsigned short* __restrict__ dst_s,
    const float* __restrict__ Ps_cur, const float* __restrict__ Pd_cur,
    float* __restrict__ hpart, const int* __restrict__ off,
    const float* __restrict__ wbuf,
    float* __restrict__ Ps_next, float* __restrict__ Pd_next,
    float* __restrict__ aggR, float* __restrict__ aggW) {
  int t = threadIdx.x;
  if (blockIdx.x >= NB2_GRID) {
    // ---------------- edge body ----------------
    __shared__ float sWC[EF * EF];
    __shared__ float sBC[EF];
    __shared__ float sZ[256 * ZSTR];   // 17.4 KB, stride-17 (free 2-way)
    __shared__ int sInfo[2];
    int b = blockIdx.x - NB2_GRID;
    int base = b * 256;
    int end = base + 256; if (end > N_EDGES) end = N_EDGES;
    sWC[t] = wbuf[W_COMB + t];
    if (t < EF) sBC[t] = wbuf[B_COMB + t];
    if (t == 0) { sInfo[0] = dst_s[base]; sInfo[1] = dst_s[end - 1]; }
    __syncthreads();
    int q = base + t;
    if (q < end) {
      int s = src_s[q], d = dst_s[q];
      float e[EF];
      const float4* ebp = (const float4*)(e_src + (size_t)q * EF);
#pragma unroll
      for (int k4 = 0; k4 < 4; ++k4) {
        float4 v = ebp[k4];
        e[4 * k4] = v.x; e[4 * k4 + 1] = v.y; e[4 * k4 + 2] = v.z; e[4 * k4 + 3] = v.w;
      }
      const float4* ps = (const float4*)(Ps_cur + (size_t)s * EF);
      const float4* pd = (const float4*)(Pd_cur + (size_t)d * EF);
      float z[EF];
#pragma unroll
      for (int i4 = 0; i4 < 4; ++i4) {
        float4 a = ps[i4], bb = pd[i4];
        z[4 * i4 + 0] = sBC[4 * i4 + 0] + a.x + bb.x;
        z[4 * i4 + 1] = sBC[4 * i4 + 1] + a.y + bb.y;
        z[4 * i4 + 2] = sBC[4 * i4 + 2] + a.z + bb.z;
        z[4 * i4 + 3] = sBC[4 * i4 + 3] + a.w + bb.w;
      }
#pragma unroll
      for (int k = 0; k < EF; ++k) {
        float v = e[k];
        const float4* wr = (const float4*)(sWC + k * EF);
#pragma unroll
        for (int i4 = 0; i4 < 4; ++i4) {
          float4 w = wr[i4];
          z[4 * i4 + 0] = fmaf(v, w.x, z[4 * i4 + 0]);
          z[4 * i4 + 1] = fmaf(v, w.y, z[4 * i4 + 1]);
          z[4 * i4 + 2] = fmaf(v, w.z, z[4 * i4 + 2]);
          z[4 * i4 + 3] = fmaf(v, w.w, z[4 * i4 + 3]);
        }
      }
#pragma unroll
      for (int i = 0; i < EF; ++i) z[i] = sigmoidf_(z[i]);
      float4* obp = (float4*)(e_dst + (size_t)q * EF);
#pragma unroll
      for (int i4 = 0; i4 < 4; ++i4)
        obp[i4] = make_float4(z[4 * i4], z[4 * i4 + 1], z[4 * i4 + 2], z[4 * i4 + 3]);
      float* zr = sZ + t * ZSTR;
#pragma unroll
      for (int j = 0; j < EF; ++j) zr[j] = z[j];
    }
    __syncthreads();
    // conflict-free segment reduction: node r = t>>3, features f, f+1
    int d_first = sInfo[0];
    int span = sInfo[1] - d_first + 1;
    int f = (t & 7) * 2;
    for (int r = t >> 3; r < span; r += 32) {
      int dd = d_first + r;
      int lo = off[dd], hi = off[dd + 1];
      int ql = lo > base ? lo : base;
      int qh = hi < end ? hi : end;
      float s0 = 0.f, s1 = 0.f;
      for (int qq = ql; qq < qh; ++qq) {
        const float* zr = sZ + (qq - base) * ZSTR + f;
        s0 += zr[0]; s1 += zr[1];
      }
      float* grow = aggW + (size_t)dd * EF + f;
      if (lo >= base && hi <= end) {
        grow[0] = s0; grow[1] = s1;
      } else {
        atomicAdd(&grow[0], s0);
        atomicAdd(&grow[1], s1);
      }
    }
    return;
  }
  // ---------------- node body (2 threads/node, agg-fed) ----------------
  __shared__ float sWnc[EF * NF];
  __shared__ float sbvec[NF];
  __shared__ float sPRJ[2048];
  __shared__ float sPB[64];
  for (int i = t; i < 2048; i += 256) sPRJ[i] = wbuf[W_SD + i];
  for (int i = t; i < EF * NF; i += 256) sWnc[i] = wbuf[W_NC + i];
  if (t < 64) sPB[t] = wbuf[B_SD + t];
  if (t < NF) sbvec[t] = wbuf[B_VEC + t];
  __syncthreads();
  int gid = blockIdx.x * 256 + t;
  int n = gid >> 1, p = gid & 1;
  if (n >= N_NODES) return;
  int o0 = off[n], o1 = off[n + 1];

  float* ar = aggR + (size_t)n * EF + 8 * p;
  float4 a0 = ((const float4*)ar)[0];
  float4 a1 = ((const float4*)ar)[1];
  ((float4*)ar)[0] = make_float4(0.f, 0.f, 0.f, 0.f);   // zero for edge_{i+1}
  ((float4*)ar)[1] = make_float4(0.f, 0.f, 0.f, 0.f);
  float s8[8] = {a0.x, a0.y, a0.z, a0.w, a1.x, a1.y, a1.z, a1.w};

  float z[NF];
  if (p == 0) {
    const float4* hp = (const float4*)(hpart + (size_t)n * NF);
#pragma unroll
    for (int j4 = 0; j4 < 8; ++j4) {
      float4 v = hp[j4];
      z[4 * j4] = v.x; z[4 * j4 + 1] = v.y; z[4 * j4 + 2] = v.z; z[4 * j4 + 3] = v.w;
    }
  } else {
    float dg = (float)(o1 - o0);
#pragma unroll
    for (int j = 0; j < NF; ++j) z[j] = dg * sbvec[j];
  }
#pragma unroll
  for (int k = 0; k < 8; ++k) {
    float v = s8[k];
    const float4* wr = (const float4*)(sWnc + (8 * p + k) * NF);
#pragma unroll
    for (int j4 = 0; j4 < 8; ++j4) {
      float4 w = wr[j4];
      z[4 * j4 + 0] = fmaf(v, w.x, z[4 * j4 + 0]);
      z[4 * j4 + 1] = fmaf(v, w.y, z[4 * j4 + 1]);
      z[4 * j4 + 2] = fmaf(v, w.z, z[4 * j4 + 2]);
      z[4 * j4 + 3] = fmaf(v, w.w, z[4 * j4 + 3]);
    }
  }
#pragma unroll
  for (int j = 0; j < NF; ++j) z[j] += __shfl_xor(z[j], 1, 64);
#pragma unroll
  for (int j = 0; j < NF; ++j) z[j] = sigmoidf_(z[j]);

  float pr[NF];
  const float* pb = sPB + p * 32;
#pragma unroll
  for (int j = 0; j < NF; ++j) pr[j] = pb[j];
  const float* wbase = sPRJ + p * 1024;
  for (int k = 0; k < NF; ++k) {
    float v = z[k];
    const float4* wr = (const float4*)(wbase + k * NF);
#pragma unroll
    for (int j4 = 0; j4 < 8; ++j4) {
      float4 w = wr[j4];
      pr[4 * j4 + 0] = fmaf(v, w.x, pr[4 * j4 + 0]);
      pr[4 * j4 + 1] = fmaf(v, w.y, pr[4 * j4 + 1]);
      pr[4 * j4 + 2] = fmaf(v, w.z, pr[4 * j4 + 2]);
      pr[4 * j4 + 3] = fmaf(v, w.w, pr[4 * j4 + 3]);
    }
  }
  if (p == 0) {
    float4* a = (float4*)(Ps_next + (size_t)n * EF);
    a[0] = make_float4(pr[0], pr[1], pr[2], pr[3]);
    a[1] = make_float4(pr[4], pr[5], pr[6], pr[7]);
    a[2] = make_float4(pr[8], pr[9], pr[10], pr[11]);
    a[3] = make_float4(pr[12], pr[13], pr[14], pr[15]);
    float4* b = (float4*)(Pd_next + (size_t)n * EF);
    b[0] = make_float4(pr[16], pr[17], pr[18], pr[19]);
    b[1] = make_float4(pr[20], pr[21], pr[22], pr[23]);
    b[2] = make_float4(pr[24], pr[25], pr[26], pr[27]);
    b[3] = make_float4(pr[28], pr[29], pr[30], pr[31]);
  } else {
    float4* h = (float4*)(hpart + (size_t)n * NF);
#pragma unroll
    for (int j4 = 0; j4 < 8; ++j4)
      h[j4] = make_float4(pr[4 * j4], pr[4 * j4 + 1], pr[4 * j4 + 2], pr[4 * j4 + 3]);
  }
}

// ---------------------------------------------------------------------------
// final node pass (iter 12), agg-fed: z/sig as above, then out = sig@Wnf+bnf
// ---------------------------------------------------------------------------
__global__ void __launch_bounds__(256) final_kernel(
    const float* __restrict__ aggR, const float* __restrict__ hpart,
    const int* __restrict__ off, const float* __restrict__ wbuf,
    float* __restrict__ out) {
  __shared__ float sWnc[EF * NF];
  __shared__ float sbvec[NF];
  __shared__ float sWNF[NF * NC];
  __shared__ float sBNF[NC];
  for (int i = threadIdx.x; i < EF * NF; i += 256) sWnc[i] = wbuf[W_NC + i];
  if (threadIdx.x < NF) sbvec[threadIdx.x] = wbuf[B_VEC + threadIdx.x];
  if (threadIdx.x < NF * NC) sWNF[threadIdx.x] = wbuf[W_NF + threadIdx.x];
  if (threadIdx.x < NC) sBNF[threadIdx.x] = wbuf[B_NF + threadIdx.x];
  __syncthreads();
  int gid = blockIdx.x * 256 + threadIdx.x;
  int n = gid >> 1, p = gid & 1;
  if (n >= N_NODES) return;
  int o0 = off[n], o1 = off[n + 1];

  const float4* ap = (const float4*)(aggR + (size_t)n * EF + 8 * p);
  float4 a0 = ap[0], a1 = ap[1];
  float s8[8] = {a0.x, a0.y, a0.z, a0.w, a1.x, a1.y, a1.z, a1.w};

  float z[NF];
  if (p == 0) {
    const float4* hp = (const float4*)(hpart + (size_t)n * NF);
#pragma unroll
    for (int j4 = 0; j4 < 8; ++j4) {
      float4 v = hp[j4];
      z[4 * j4] = v.x; z[4 * j4 + 1] = v.y; z[4 * j4 + 2] = v.z; z[4 * j4 + 3] = v.w;
    }
  } else {
    float dg = (float)(o1 - o0);
#pragma unroll
    for (int j = 0; j < NF; ++j) z[j] = dg * sbvec[j];
  }
#pragma unroll
  for (int k = 0; k < 8; ++k) {
    float v = s8[k];
    const float4* wr = (const float4*)(sWnc + (8 * p + k) * NF);
#pragma unroll
    for (int j4 = 0; j4 < 8; ++j4) {
      float4 w = wr[j4];
      z[4 * j4 + 0] = fmaf(v, w.x, z[4 * j4 + 0]);
      z[4 * j4 + 1] = fmaf(v, w.y, z[4 * j4 + 1]);
      z[4 * j4 + 2] = fmaf(v, w.z, z[4 * j4 + 2]);
      z[4 * j4 + 3] = fmaf(v, w.w, z[4 * j4 + 3]);
    }
  }
#pragma unroll
  for (int j = 0; j < NF; ++j) z[j] += __shfl_xor(z[j], 1, 64);
#pragma unroll
  for (int j = 0; j < NF; ++j) z[j] = sigmoidf_(z[j]);

  float o[NC];
  float pm = (p == 0) ? 1.0f : 0.0f;
#pragma unroll
  for (int c = 0; c < NC; ++c) o[c] = pm * sBNF[c];
  for (int k = 0; k < 16; ++k) {
    float v = z[16 * p + k];
    const float* wr = sWNF + (16 * p + k) * NC;
#pragma unroll
    for (int c = 0; c < NC; ++c) o[c] = fmaf(v, wr[c], o[c]);
  }
#pragma unroll
  for (int c = 0; c < NC; ++c) o[c] += __shfl_xor(o[c], 1, 64);
  if (p == 0) {
    float4* op = (float4*)(out + (size_t)n * NC);
    op[0] = make_float4(o[0], o[1], o[2], o[3]);
    op[1] = make_float4(o[4], o[5], o[6], o[7]);
  }
}

// ---------------------------------------------------------------------------
extern "C" void kernel_launch(void* const* d_in, const int* in_sizes, int n_in,
                              void* d_out, int out_size, void* d_ws, size_t ws_size,
                              hipStream_t stream) {
  const float* node_feat = (const float*)d_in[0];
  const float* edge_feat = (const float*)d_in[1];
  const int*   src = (const int*)d_in[2];
  const int*   dst = (const int*)d_in[3];
  const float* Wn  = (const float*)d_in[4];
  const float* bn  = (const float*)d_in[5];
  const float* We  = (const float*)d_in[6];
  const float* be  = (const float*)d_in[7];
  const float* Wem = (const float*)d_in[8];
  const float* bem = (const float*)d_in[9];
  const float* Wnm = (const float*)d_in[10];
  const float* bnm = (const float*)d_in[11];
  const float* Wfc = (const float*)d_in[12];
  const float* bfc = (const float*)d_in[13];
  float* out = (float*)d_out;

  float* ws    = (float*)d_ws;
  float* e_b0  = ws;                                   // 3,840,000 f
  float* e_b1  = e_b0 + (size_t)N_EDGES * EF;          // 3,840,000 f
  float* hpart = e_b1 + (size_t)N_EDGES * EF;          //   960,000 f
  float* Ps0   = hpart + (size_t)N_NODES * NF;         //   480,000 f
  float* Pd0   = Ps0 + (size_t)N_NODES * EF;
  float* Ps1   = Pd0 + (size_t)N_NODES * EF;
  float* Pd1   = Ps1 + (size_t)N_NODES * EF;
  float* G0    = Pd1 + (size_t)N_NODES * EF;           //   480,000 f
  float* G1    = G0 + (size_t)N_NODES * EF;            //   480,000 f
  float* wbuf  = G1 + (size_t)N_NODES * EF;            //     4,096 f
  int* cnt     = (int*)(wbuf + 4096);                  //    30,000 i
  int* off     = cnt + N_NODES;                        //    30,001 i
  int* cursor  = off + N_NODES + 1;                    //    30,000 i
  unsigned short* src_s = (unsigned short*)(cursor + N_NODES);  // 240,000 u16
  unsigned short* dst_s = src_s + N_EDGES;                      // 240,000 u16
  float* PsA[2] = {Ps0, Ps1};
  float* PdA[2] = {Pd0, Pd1};
  float* EbA[2] = {e_b0, e_b1};
  float* GA[2]  = {G0, G1};

  // --- preamble: counting sort + weight folding; zero both agg buffers ---
  hipMemsetAsync(cnt, 0, (size_t)N_NODES * sizeof(int), stream);
  hipMemsetAsync(G0, 0, (size_t)2 * N_NODES * EF * sizeof(float), stream);
  hist_pre_kernel<<<EB_GRID + 1, 256, 0, stream>>>(
      dst, cnt, Wn, bn, We, be, Wem, bem, Wnm, bnm, Wfc, bfc, wbuf);
  scan_kernel<<<1, 1024, 0, stream>>>(cnt, off, cursor);
  scatter_init_kernel<<<EB_GRID + NB2_GRID, 256, 0, stream>>>(
      edge_feat, src, dst, cursor, src_s, dst_s, e_b0,
      node_feat, wbuf, Ps1, Pd1, hpart);
  // one-time gather: agg0 = segsum(initial sorted e rows) -> G0
  agg0_kernel<<<NB2_GRID, 256, 0, stream>>>(e_b0, off, G0);

  // 11 fused (node_i || edge_i) passes.
  // node_i reads GA[(i+1)&1] (then zeroes it); edge_i writes GA[i&1].
  // e double-buffer: both read EbA[(i+1)&1], edge writes EbA[i&1].
  // P ping-pong: edge_i reads P[i&1]; node_i writes P[(i+1)&1].
  for (int i = 1; i <= 11; ++i) {
    fused4_kernel<<<NB2_GRID + EB_GRID, 256, 0, stream>>>(
        EbA[(i + 1) & 1], EbA[i & 1], src_s, dst_s,
        PsA[i & 1], PdA[i & 1], hpart, off, wbuf,
        PsA[(i + 1) & 1], PdA[(i + 1) & 1],
        GA[(i + 1) & 1], GA[i & 1]);
  }
  // node pass 12 + output head; edge_11 wrote agg into GA[1].
  final_kernel<<<NB2_GRID, 256, 0, stream>>>(GA[1], hpart, off, wbuf, out);
}